// Round 3
// baseline (454.066 us; speedup 1.0000x reference)
//
#include <hip/hip_runtime.h>

// CRC-24 encoder: out = [bits | parity(bits @ G mod 2)]
// BATCH=16384 rows, K=4096 bits/row, 24 CRC bits, OUTW=4120.
// Memory-bound: ~538 MB mandatory traffic -> ~85us floor at 6.3 TB/s.
//
// R3: gm table register-resident (16 x uint4 = 64 VGPR/lane covers the whole
// 16 KB table per wave), 4 consecutive rows per wave to amortize it; inner
// loop is pure load->store->3 VALU stream with constant-index gm regs.

constexpr int K       = 4096;
constexpr int CRC_LEN = 24;
constexpr int OUTW    = K + CRC_LEN;   // 4120 floats (row stride 16480 B)
constexpr int BATCH   = 16384;
constexpr int ROWS_PER_WAVE = 4;

typedef float  vfloat4 __attribute__((ext_vector_type(4)));
typedef unsigned int vuint4 __attribute__((ext_vector_type(4)));

// Pack each g_mat row (24 floats of 0/1) into one 24-bit word -> d_ws (16 KB).
__global__ void pack_gmat_kernel(const float* __restrict__ g,
                                 unsigned int* __restrict__ gm) {
    int i = blockIdx.x * blockDim.x + threadIdx.x;
    if (i < K) {
        unsigned int w = 0u;
        #pragma unroll
        for (int j = 0; j < CRC_LEN; ++j)
            w |= (g[i * CRC_LEN + j] != 0.0f ? 1u : 0u) << j;
        gm[i] = w;
    }
}

// 4 waves/block, 4 rows/wave. grid = BATCH/16 = 1024 blocks.
__global__ __launch_bounds__(256) void crc_encode_kernel(
        const float* __restrict__ in,
        const unsigned int* __restrict__ gm,
        float* __restrict__ out) {
    const int t      = threadIdx.x;
    const int lane   = t & 63;
    const int waveId = blockIdx.x * 4 + (t >> 6);
    const int row0   = waveId * ROWS_PER_WAVE;   // 4 consecutive rows

    const vuint4* gm4 = (const vuint4*)gm;

    // Whole 16 KB gm table register-resident across the wave:
    // lane L holds gm4[it*64+L] for it=0..15 (16 uint4 = 64 VGPRs).
    vuint4 gmr[16];
    #pragma unroll
    for (int it = 0; it < 16; ++it)
        gmr[it] = gm4[it * 64 + lane];

    #pragma unroll
    for (int r = 0; r < ROWS_PER_WAVE; ++r) {
        const int row = row0 + r;
        const vfloat4* in4  = (const vfloat4*)(in  + (size_t)row * K);
        vfloat4*       out4 = (vfloat4*)(out + (size_t)row * OUTW);

        unsigned int acc = 0u;
        #pragma unroll   // full unroll: gmr indices stay compile-time constant
        for (int it = 0; it < 16; ++it) {
            vfloat4 b = in4[it * 64 + lane];
            out4[it * 64 + lane] = b;                 // fused concat copy
            acc ^= (b.x != 0.0f) ? gmr[it].x : 0u;
            acc ^= (b.y != 0.0f) ? gmr[it].y : 0u;
            acc ^= (b.z != 0.0f) ? gmr[it].z : 0u;
            acc ^= (b.w != 0.0f) ? gmr[it].w : 0u;
        }

        // 64-lane XOR butterfly: every lane ends with the full parity word.
        #pragma unroll
        for (int off = 32; off >= 1; off >>= 1)
            acc ^= __shfl_xor(acc, off);

        // 24 parity floats as 6 float4 stores (lanes 0..5).
        if (lane < CRC_LEN / 4) {
            vfloat4 p;
            p.x = (float)((acc >> (4 * lane + 0)) & 1u);
            p.y = (float)((acc >> (4 * lane + 1)) & 1u);
            p.z = (float)((acc >> (4 * lane + 2)) & 1u);
            p.w = (float)((acc >> (4 * lane + 3)) & 1u);
            out4[K / 4 + lane] = p;
        }
    }
}

extern "C" void kernel_launch(void* const* d_in, const int* in_sizes, int n_in,
                              void* d_out, int out_size, void* d_ws, size_t ws_size,
                              hipStream_t stream) {
    const float* bits = (const float*)d_in[0];   // (16384, 4096) float32 of 0/1
    const float* g    = (const float*)d_in[1];   // (4096, 24)   float32 of 0/1
    float* out        = (float*)d_out;           // (16384, 4120) float32
    unsigned int* gm  = (unsigned int*)d_ws;     // 4096 packed words (16 KB)

    pack_gmat_kernel<<<K / 256, 256, 0, stream>>>(g, gm);
    crc_encode_kernel<<<BATCH / (4 * ROWS_PER_WAVE), 256, 0, stream>>>(bits, gm, out);
}